// Round 2
// baseline (573.126 us; speedup 1.0000x reference)
//
#include <hip/hip_runtime.h>
#include <stdint.h>
#include <stddef.h>

typedef unsigned short u16;
typedef unsigned int u32;
typedef __attribute__((ext_vector_type(8))) short s8v;   // 8 bf16 = one MFMA A/B frag
typedef __attribute__((ext_vector_type(4))) short s4v;
typedef __attribute__((ext_vector_type(4))) float f4v;   // MFMA C/D frag / float4

#define D_MODEL 2048
#define NH 16
#define DK 128

__device__ __forceinline__ float b2f(u16 u) {
    union { u32 i; float f; } v; v.i = ((u32)u) << 16; return v.f;
}
__device__ __forceinline__ u16 f2b(float f) {  // RNE; values here always finite
    u32 u = __builtin_bit_cast(u32, f);
    u32 r = (u + 0x7fffu + ((u >> 16) & 1u)) >> 16;
    return (u16)r;
}
__device__ __forceinline__ f4v mfma16(s8v a, s8v b, f4v c) {
    return __builtin_amdgcn_mfma_f32_16x16x32_bf16(a, b, c, 0, 0, 0);
}
// async global->LDS, 16B/lane. LDS dest must be the WAVE-UNIFORM base; HW adds lane*16.
__device__ __forceinline__ void gload_lds16(const void* g, void* l) {
    __builtin_amdgcn_global_load_lds(
        (const __attribute__((address_space(1))) u32*)(uintptr_t)g,
        (__attribute__((address_space(3))) u32*)(uintptr_t)l, 16, 0, 0);
}

__device__ __forceinline__ void store_out(u16* p, float v)   { *p = f2b(v); }
__device__ __forceinline__ void store_out(float* p, float v) { *p = v; }

// ---------------------------------------------------------------------------
// fp32 -> bf16 conversion pass. grid.y selects segment (0: x, 1..4: weights).
// 8 elems/thread: 2x float4 in, 1x 16B out.
// ---------------------------------------------------------------------------
__global__ __launch_bounds__(256) void cvt_bf16(
    const float* __restrict__ s0, const float* __restrict__ s1,
    const float* __restrict__ s2, const float* __restrict__ s3,
    const float* __restrict__ s4,
    u16* __restrict__ d0, u16* __restrict__ d1, u16* __restrict__ d2,
    u16* __restrict__ d3, u16* __restrict__ d4,
    int n0, int nw)
{
    const int seg = blockIdx.y;
    const float* s = (seg == 0) ? s0 : (seg == 1) ? s1 : (seg == 2) ? s2 : (seg == 3) ? s3 : s4;
    u16*         d = (seg == 0) ? d0 : (seg == 1) ? d1 : (seg == 2) ? d2 : (seg == 3) ? d3 : d4;
    const int    n = (seg == 0) ? n0 : nw;
    int i = (blockIdx.x * 256 + threadIdx.x) * 8;
    if (i >= n) return;
    f4v a = *(const f4v*)(s + i);
    f4v b = *(const f4v*)(s + i + 4);
    s8v o;
    o[0] = (short)f2b(a[0]); o[1] = (short)f2b(a[1]);
    o[2] = (short)f2b(a[2]); o[3] = (short)f2b(a[3]);
    o[4] = (short)f2b(b[0]); o[5] = (short)f2b(b[1]);
    o[6] = (short)f2b(b[2]); o[7] = (short)f2b(b[3]);
    *(s8v*)(d + i) = o;
}

// ---------------------------------------------------------------------------
// GEMM: C[M,N] = A[M,K] * B^T  (B given [N,K] row-major). m97 structure:
// 128x128 tile, BK=32, 4 waves of 64x64, global_load_lds width-16 staging.
// grid.z selects (B,C) pair so QKV is one launch. OutT = u16 (bf16) or float.
// ---------------------------------------------------------------------------
template<typename OutT>
__global__ __launch_bounds__(256) void gemm_bt3(
    const u16* __restrict__ A,
    const u16* __restrict__ B0, const u16* __restrict__ B1, const u16* __restrict__ B2,
    OutT* __restrict__ C0, OutT* __restrict__ C1, OutT* __restrict__ C2,
    int M, int N, int K)
{
    const int z = blockIdx.z;
    const u16* Bp = (z == 0) ? B0 : (z == 1) ? B1 : B2;
    OutT*      Cp = (z == 0) ? C0 : (z == 1) ? C1 : C2;

    __shared__ short As[128 * 32];   // [row][k] 8 KB
    __shared__ short Bs[128 * 32];

    const int t    = threadIdx.x;
    const int lane = t & 63;
    const int w    = t >> 6;
    const int wm   = (w >> 1) * 64;
    const int wn   = (w & 1) * 64;
    const int m0   = blockIdx.x * 128;
    const int n0   = blockIdx.y * 128;

    // staging map: chunk = issue*256 + t ; row = chunk>>2 ; col8 = (chunk&3)*8
    const int r0 = t >> 2;
    const int c0 = (t & 3) * 8;

    f4v acc[4][4];
#pragma unroll
    for (int i = 0; i < 4; i++)
#pragma unroll
        for (int j = 0; j < 4; j++) acc[i][j] = (f4v){0.f, 0.f, 0.f, 0.f};

    const u16* gA = A  + (size_t)(m0 + r0) * K + c0;
    const u16* gB = Bp + (size_t)(n0 + r0) * K + c0;
    char* lA = (char*)As + (size_t)(w * 64) * 16;   // wave-uniform LDS bases
    char* lB = (char*)Bs + (size_t)(w * 64) * 16;

    const int fr = lane & 15;
    const int kc = (lane >> 4) * 8;

    for (int kt = 0; kt < K; kt += 32) {
        __syncthreads();                         // prev compute done reading LDS
        gload_lds16(gA + kt,                  lA);
        gload_lds16(gA + (size_t)64 * K + kt, lA + 4096);
        gload_lds16(gB + kt,                  lB);
        gload_lds16(gB + (size_t)64 * K + kt, lB + 4096);
        __syncthreads();                         // compiler drains vmcnt(0) before barrier

        s8v aF[4], bF[4];
#pragma unroll
        for (int mi = 0; mi < 4; mi++)
            aF[mi] = *(const s8v*)&As[(wm + mi * 16 + fr) * 32 + kc];
#pragma unroll
        for (int ni = 0; ni < 4; ni++)
            bF[ni] = *(const s8v*)&Bs[(wn + ni * 16 + fr) * 32 + kc];
#pragma unroll
        for (int mi = 0; mi < 4; mi++)
#pragma unroll
            for (int ni = 0; ni < 4; ni++)
                acc[mi][ni] = mfma16(aF[mi], bF[ni], acc[mi][ni]);
    }

    // epilogue: C row = (lane>>4)*4+reg, col = lane&15  (m89-verified layout)
    const int rg = (lane >> 4) * 4;
#pragma unroll
    for (int mi = 0; mi < 4; mi++)
#pragma unroll
        for (int ni = 0; ni < 4; ni++) {
            size_t base = (size_t)(m0 + wm + mi * 16 + rg) * N + (n0 + wn + ni * 16 + fr);
#pragma unroll
            for (int r = 0; r < 4; r++)
                store_out(&Cp[base + (size_t)r * N], acc[mi][ni][r]);
        }
}

// ---------------------------------------------------------------------------
// RoPE in-place on Q and K ([B*S, 2048] bf16). One bf16 pair (dword) per
// thread, fully coalesced. Folds 1/sqrt(DK) into Q.
// ---------------------------------------------------------------------------
__global__ void rope_kernel(u32* __restrict__ Q, u32* __restrict__ Kb,
                            const int* __restrict__ pos, int total, int S)
{
    int idx = blockIdx.x * 256 + threadIdx.x;
    if (idx >= total) return;
    int row = idx >> 10;            // 1024 pairs per row
    int pr  = idx & 1023;
    int i   = pr & 63;              // pair index within head
    int s   = row % S;
    float p    = (float)pos[s];
    float freq = __expf((float)i * -0.14391156831212787f);  // 10000^(-i/64)
    float ang  = p * freq;
    float c = cosf(ang), sn = sinf(ang);

    u32 qp = Q[idx];
    float qe = b2f((u16)(qp & 0xffffu)), qo = b2f((u16)(qp >> 16));
    const float sc = 0.08838834764831845f;  // 1/sqrt(128)
    float qe2 = (qe * c - qo * sn) * sc;
    float qo2 = (qe * sn + qo * c) * sc;
    Q[idx] = (u32)f2b(qe2) | ((u32)f2b(qo2) << 16);

    u32 kp = Kb[idx];
    float ke = b2f((u16)(kp & 0xffffu)), ko = b2f((u16)(kp >> 16));
    float ke2 = ke * c - ko * sn;
    float ko2 = ke * sn + ko * c;
    Kb[idx] = (u32)f2b(ke2) | ((u32)f2b(ko2) << 16);
}

// ---------------------------------------------------------------------------
// Causal flash attention. Block = one (b, h, 64-q-row tile); 4 waves x 16 q.
// Swapped QK^T: S^T = mfma(K, Q) so each lane owns ONE q (col = lane&15) ->
// softmax reduce = 2 shfl_xor; O^T = mfma(V^T, P^T) keeps the same per-lane q,
// so rescale/normalize need no cross-lane traffic. Each wave reads/writes ONLY
// its own 16 Q rows of Qs (no cross-wave hazard on the final O transpose).
// ---------------------------------------------------------------------------
#define QT  64
#define KVT 64
#define KP  136   // Q/K lds row stride (elems): 16B-aligned, 2-way bank alias
#define VP  72    // Vt kv-stride
#define PP  72    // P  kv-stride

__global__ __launch_bounds__(256) void attn_kernel(
    const u16* __restrict__ Qg, const u16* __restrict__ Kg, const u16* __restrict__ Vg,
    u16* __restrict__ Og, int S)
{
    __shared__ short Qs[QT * KP];      // 17408 B (reused for O at the end)
    __shared__ short Ks[KVT * KP];     // 17408 B
    __shared__ short Vt[DK * VP];      // 18432 B  V^T: [d][kv]
    __shared__ short Ps[4][16 * PP];   //  9216 B  per-wave P: [q][kv]

    const int t    = threadIdx.x;
    const int lane = t & 63;
    const int w    = t >> 6;
    const int fr   = lane & 15;
    const int g4   = lane >> 4;

    const int qt = blockIdx.x;
    const int h  = blockIdx.y;
    const int b  = blockIdx.z;
    const int q0 = qt * QT;

    const size_t base = ((size_t)b * S) * D_MODEL + (size_t)h * DK;
    const u16* Qb = Qg + base;
    const u16* Kb = Kg + base;
    const u16* Vb = Vg + base;
    u16*       Ob = Og + base;

    // stage Q tile [64][128] (rows stride D_MODEL in global)
#pragma unroll
    for (int c = 0; c < 4; c++) {
        int chunk = c * 256 + t;
        int row = chunk >> 4, c8 = (chunk & 15) * 8;
        s8v v = *(const s8v*)(Qb + (size_t)(q0 + row) * D_MODEL + c8);
        *(s8v*)&Qs[row * KP + c8] = v;
    }

    const int qw  = w * 16 + fr;     // this lane's local q
    const int q_g = q0 + qw;
    float m_st = -1e30f, l_st = 0.f;
    f4v accO[8];                     // O^T frags: row d = df*16 + g4*4 + r, col q = fr
#pragma unroll
    for (int i = 0; i < 8; i++) accO[i] = (f4v){0.f, 0.f, 0.f, 0.f};

    const int nkv = qt + 1;
    for (int kt = 0; kt < nkv; kt++) {
        const int kv0 = kt * KVT;
        __syncthreads();             // prev iter done reading Ks/Vt/Ps (+Q stage done)
        // stage K [64][128]
#pragma unroll
        for (int c = 0; c < 4; c++) {
            int chunk = c * 256 + t;
            int row = chunk >> 4, c8 = (chunk & 15) * 8;
            s8v v = *(const s8v*)(Kb + (size_t)(kv0 + row) * D_MODEL + c8);
            *(s8v*)&Ks[row * KP + c8] = v;
        }
        // stage V transposed -> Vt[d][kv]
#pragma unroll
        for (int c = 0; c < 4; c++) {
            int chunk = c * 256 + t;
            int row = chunk >> 4, c8 = (chunk & 15) * 8;   // row = kv, c8 = d base
            s8v v = *(const s8v*)(Vb + (size_t)(kv0 + row) * D_MODEL + c8);
#pragma unroll
            for (int j = 0; j < 8; j++)
                Vt[(c8 + j) * VP + row] = ((short*)&v)[j];
        }
        __syncthreads();

        // S^T = K * Q^T : C row = kv, col = q
        f4v sacc[4];
#pragma unroll
        for (int i = 0; i < 4; i++) sacc[i] = (f4v){0.f, 0.f, 0.f, 0.f};
#pragma unroll
        for (int ks = 0; ks < 4; ks++) {
            s8v qf = *(const s8v*)&Qs[(w * 16 + fr) * KP + ks * 32 + g4 * 8];
#pragma unroll
            for (int kf = 0; kf < 4; kf++) {
                s8v kfr = *(const s8v*)&Ks[(kf * 16 + fr) * KP + ks * 32 + g4 * 8];
                sacc[kf] = mfma16(kfr, qf, sacc[kf]);
            }
        }

        // causal mask + online softmax (per-lane q = q_g)
        float rowmax = -1e30f;
#pragma unroll
        for (int kf = 0; kf < 4; kf++)
#pragma unroll
            for (int r = 0; r < 4; r++) {
                int kv_g = kv0 + kf * 16 + g4 * 4 + r;
                float v = sacc[kf][r];
                v = (kv_g <= q_g) ? v : -1e30f;
                sacc[kf][r] = v;
                rowmax = fmaxf(rowmax, v);
            }
        rowmax = fmaxf(rowmax, __shfl_xor(rowmax, 16));
        rowmax = fmaxf(rowmax, __shfl_xor(rowmax, 32));
        float m_new = fmaxf(m_st, rowmax);
        float corr  = __expf(m_st - m_new);
        float rsum  = 0.f;
#pragma unroll
        for (int kf = 0; kf < 4; kf++) {
            float p0 = __expf(sacc[kf][0] - m_new);
            float p1 = __expf(sacc[kf][1] - m_new);
            float p2 = __expf(sacc[kf][2] - m_new);
            float p3 = __expf(sacc[kf][3] - m_new);
            rsum += (p0 + p1) + (p2 + p3);
            s4v pk;
            pk[0] = (short)f2b(p0); pk[1] = (short)f2b(p1);
            pk[2] = (short)f2b(p2); pk[3] = (short)f2b(p3);
            // P[q][kv]: kv = kf*16 + g4*4 + r consecutive -> one b64 write
            *(s4v*)&Ps[w][fr * PP + kf * 16 + g4 * 4] = pk;
        }
        rsum += __shfl_xor(rsum, 16);
        rsum += __shfl_xor(rsum, 32);
        l_st = l_st * corr + rsum;
        m_st = m_new;
#pragma unroll
        for (int i = 0; i < 8; i++) {
            accO[i][0] *= corr; accO[i][1] *= corr;
            accO[i][2] *= corr; accO[i][3] *= corr;
        }
        // O^T += V^T * P^T  (same-wave LDS RAW on Ps: DS pipe is in-order)
#pragma unroll
        for (int ks = 0; ks < 2; ks++) {
            s8v pf = *(const s8v*)&Ps[w][fr * PP + ks * 32 + g4 * 8];
#pragma unroll
            for (int df = 0; df < 8; df++) {
                s8v vf = *(const s8v*)&Vt[(df * 16 + fr) * VP + ks * 32 + g4 * 8];
                accO[df] = mfma16(vf, pf, accO[df]);
            }
        }
    }

    // normalize, transpose O^T -> O through Qs (wave-private rows), then
    // coalesced global store.
    float inv = 1.f / l_st;
#pragma unroll
    for (int df = 0; df < 8; df++) {
        s4v ov;
        ov[0] = (short)f2b(accO[df][0] * inv);
        ov[1] = (short)f2b(accO[df][1] * inv);
        ov[2] = (short)f2b(accO[df][2] * inv);
        ov[3] = (short)f2b(accO[df][3] * inv);
        *(s4v*)&Qs[qw * KP + df * 16 + g4 * 4] = ov;
    }
    __syncthreads();
#pragma unroll
    for (int c = 0; c < 4; c++) {
        int chunk = c * 256 + t;
        int row = chunk >> 4, c8 = (chunk & 15) * 8;
        s8v v = *(const s8v*)&Qs[row * KP + c8];
        *(s8v*)(Ob + (size_t)(q0 + row) * D_MODEL + c8) = v;
    }
}

// ---------------------------------------------------------------------------
extern "C" void kernel_launch(void* const* d_in, const int* in_sizes, int n_in,
                              void* d_out, int out_size, void* d_ws, size_t ws_size,
                              hipStream_t stream)
{
    const float* x  = (const float*)d_in[0];
    const float* wq = (const float*)d_in[1];
    const float* wk = (const float*)d_in[2];
    const float* wv = (const float*)d_in[3];
    const float* wo = (const float*)d_in[4];
    const int*   tp = (const int*)d_in[5];

    const int S  = in_sizes[5];
    const int BS = in_sizes[0] / D_MODEL;   // B*S rows (4096)
    const int Bn = BS / S;
    const int NW = D_MODEL * D_MODEL;       // weight elems (4.2M)
    const int NX = BS * D_MODEL;            // x/Q/K/V/O elems (8.4M)

    // bf16 workspace layout (u16 elems):
    // [Q][K][V][Xb(->O)][Wq][Wk][Wv][Wo]  = 96 MB total
    u16* Qw  = (u16*)d_ws;
    u16* Kw  = Qw + (size_t)NX;
    u16* Vw  = Kw + (size_t)NX;
    u16* Xb  = Vw + (size_t)NX;             // reused as attention output O
    u16* Wqb = Xb + (size_t)NX;
    u16* Wkb = Wqb + (size_t)NW;
    u16* Wvb = Wkb + (size_t)NW;
    u16* Wob = Wvb + (size_t)NW;

    // fp32 -> bf16 conversions (x + 4 weights)
    {
        dim3 g((NX / 8 + 255) / 256, 5);
        cvt_bf16<<<g, 256, 0, stream>>>(x, wq, wk, wv, wo,
                                        Xb, Wqb, Wkb, Wvb, Wob, NX, NW);
    }

    // Q,K,V projections (one launch, z selects weight/output)
    dim3 gq(BS / 128, D_MODEL / 128, 3);
    gemm_bt3<u16><<<gq, 256, 0, stream>>>(Xb, Wqb, Wkb, Wvb, Qw, Kw, Vw,
                                          BS, D_MODEL, D_MODEL);

    // RoPE (in place; folds 1/sqrt(dk) into Q)
    int total = BS * (D_MODEL / 2);
    rope_kernel<<<(total + 255) / 256, 256, 0, stream>>>((u32*)Qw, (u32*)Kw, tp, total, S);

    // causal flash attention: O (bf16) into the Xb region (x is dead now)
    dim3 ga(S / QT, NH, Bn);
    attn_kernel<<<ga, 256, 0, stream>>>(Qw, Kw, Vw, Xb, S);

    // output projection -> fp32 d_out
    dim3 go(BS / 128, D_MODEL / 128, 1);
    gemm_bt3<float><<<go, 256, 0, stream>>>(Xb, Wob, Wob, Wob,
                                            (float*)d_out, (float*)d_out, (float*)d_out,
                                            BS, D_MODEL, D_MODEL);
}

// Round 4
// 334.669 us; speedup vs baseline: 1.7125x; 1.7125x over previous
//
#include <hip/hip_runtime.h>
#include <stdint.h>
#include <stddef.h>

typedef unsigned short u16;
typedef unsigned int u32;
typedef __attribute__((ext_vector_type(8))) short s8v;   // 8 bf16 = one MFMA A/B frag
typedef __attribute__((ext_vector_type(4))) short s4v;
typedef __attribute__((ext_vector_type(4))) float f4v;   // MFMA C/D frag / float4

#define D_MODEL 2048
#define NH 16
#define DK 128

__device__ __forceinline__ float b2f(u16 u) {
    union { u32 i; float f; } v; v.i = ((u32)u) << 16; return v.f;
}
__device__ __forceinline__ u16 f2b(float f) {  // RNE; values here always finite
    u32 u = __builtin_bit_cast(u32, f);
    u32 r = (u + 0x7fffu + ((u >> 16) & 1u)) >> 16;
    return (u16)r;
}
__device__ __forceinline__ float fexp2(float x) {        // native v_exp_f32 (base-2)
    return __builtin_amdgcn_exp2f(x);
}
__device__ __forceinline__ f4v mfma16(s8v a, s8v b, f4v c) {
    return __builtin_amdgcn_mfma_f32_16x16x32_bf16(a, b, c, 0, 0, 0);
}
// async global->LDS, 16B/lane. LDS dest must be the WAVE-UNIFORM base; HW adds lane*16.
__device__ __forceinline__ void gload_lds16(const void* g, void* l) {
    __builtin_amdgcn_global_load_lds(
        (const __attribute__((address_space(1))) u32*)(uintptr_t)g,
        (__attribute__((address_space(3))) u32*)(uintptr_t)l, 16, 0, 0);
}

__device__ __forceinline__ void store_out(u16* p, float v)   { *p = f2b(v); }
__device__ __forceinline__ void store_out(float* p, float v) { *p = v; }

// ---------------------------------------------------------------------------
// fp32 -> bf16 conversion pass. grid.y selects segment (0: x, 1..4: weights).
// ---------------------------------------------------------------------------
__global__ __launch_bounds__(256) void cvt_bf16(
    const float* __restrict__ s0, const float* __restrict__ s1,
    const float* __restrict__ s2, const float* __restrict__ s3,
    const float* __restrict__ s4,
    u16* __restrict__ d0, u16* __restrict__ d1, u16* __restrict__ d2,
    u16* __restrict__ d3, u16* __restrict__ d4,
    int n0, int nw)
{
    const int seg = blockIdx.y;
    const float* s = (seg == 0) ? s0 : (seg == 1) ? s1 : (seg == 2) ? s2 : (seg == 3) ? s3 : s4;
    u16*         d = (seg == 0) ? d0 : (seg == 1) ? d1 : (seg == 2) ? d2 : (seg == 3) ? d3 : d4;
    const int    n = (seg == 0) ? n0 : nw;
    int i = (blockIdx.x * 256 + threadIdx.x) * 8;
    if (i >= n) return;
    f4v a = *(const f4v*)(s + i);
    f4v b = *(const f4v*)(s + i + 4);
    s8v o;
    o[0] = (short)f2b(a[0]); o[1] = (short)f2b(a[1]);
    o[2] = (short)f2b(a[2]); o[3] = (short)f2b(a[3]);
    o[4] = (short)f2b(b[0]); o[5] = (short)f2b(b[1]);
    o[6] = (short)f2b(b[2]); o[7] = (short)f2b(b[3]);
    *(s8v*)(d + i) = o;
}

// ---------------------------------------------------------------------------
// GEMM: C[M,N] = A[M,K] * B^T (B given [N,K] row-major). m97 structure.
// Unchanged (attribution: this round only touches attention).
// ---------------------------------------------------------------------------
template<typename OutT>
__global__ __launch_bounds__(256) void gemm_bt3(
    const u16* __restrict__ A,
    const u16* __restrict__ B0, const u16* __restrict__ B1, const u16* __restrict__ B2,
    OutT* __restrict__ C0, OutT* __restrict__ C1, OutT* __restrict__ C2,
    int M, int N, int K)
{
    const int z = blockIdx.z;
    const u16* Bp = (z == 0) ? B0 : (z == 1) ? B1 : B2;
    OutT*      Cp = (z == 0) ? C0 : (z == 1) ? C1 : C2;

    __shared__ short As[128 * 32];
    __shared__ short Bs[128 * 32];

    const int t    = threadIdx.x;
    const int lane = t & 63;
    const int w    = t >> 6;
    const int wm   = (w >> 1) * 64;
    const int wn   = (w & 1) * 64;
    const int m0   = blockIdx.x * 128;
    const int n0   = blockIdx.y * 128;

    const int r0 = t >> 2;
    const int c0 = (t & 3) * 8;

    f4v acc[4][4];
#pragma unroll
    for (int i = 0; i < 4; i++)
#pragma unroll
        for (int j = 0; j < 4; j++) acc[i][j] = (f4v){0.f, 0.f, 0.f, 0.f};

    const u16* gA = A  + (size_t)(m0 + r0) * K + c0;
    const u16* gB = Bp + (size_t)(n0 + r0) * K + c0;
    char* lA = (char*)As + (size_t)(w * 64) * 16;
    char* lB = (char*)Bs + (size_t)(w * 64) * 16;

    const int fr = lane & 15;
    const int kc = (lane >> 4) * 8;

    for (int kt = 0; kt < K; kt += 32) {
        __syncthreads();
        gload_lds16(gA + kt,                  lA);
        gload_lds16(gA + (size_t)64 * K + kt, lA + 4096);
        gload_lds16(gB + kt,                  lB);
        gload_lds16(gB + (size_t)64 * K + kt, lB + 4096);
        __syncthreads();

        s8v aF[4], bF[4];
#pragma unroll
        for (int mi = 0; mi < 4; mi++)
            aF[mi] = *(const s8v*)&As[(wm + mi * 16 + fr) * 32 + kc];
#pragma unroll
        for (int ni = 0; ni < 4; ni++)
            bF[ni] = *(const s8v*)&Bs[(wn + ni * 16 + fr) * 32 + kc];
#pragma unroll
        for (int mi = 0; mi < 4; mi++)
#pragma unroll
            for (int ni = 0; ni < 4; ni++)
                acc[mi][ni] = mfma16(aF[mi], bF[ni], acc[mi][ni]);
    }

    const int rg = (lane >> 4) * 4;
#pragma unroll
    for (int mi = 0; mi < 4; mi++)
#pragma unroll
        for (int ni = 0; ni < 4; ni++) {
            size_t base = (size_t)(m0 + wm + mi * 16 + rg) * N + (n0 + wn + ni * 16 + fr);
#pragma unroll
            for (int r = 0; r < 4; r++)
                store_out(&Cp[base + (size_t)r * N], acc[mi][ni][r]);
        }
}

// ---------------------------------------------------------------------------
// RoPE in-place on Q and K. Folds (1/sqrt(DK))*log2(e) into Q so attention
// softmax can use exp2 directly.
// ---------------------------------------------------------------------------
__global__ void rope_kernel(u32* __restrict__ Q, u32* __restrict__ Kb,
                            const int* __restrict__ pos, int total, int S)
{
    int idx = blockIdx.x * 256 + threadIdx.x;
    if (idx >= total) return;
    int row = idx >> 10;            // 1024 pairs per row
    int pr  = idx & 1023;
    int i   = pr & 63;              // pair index within head
    int s   = row % S;
    float p    = (float)pos[s];
    float freq = __expf((float)i * -0.14391156831212787f);  // 10000^(-i/64)
    float ang  = p * freq;
    float c = cosf(ang), sn = sinf(ang);

    u32 qp = Q[idx];
    float qe = b2f((u16)(qp & 0xffffu)), qo = b2f((u16)(qp >> 16));
    const float sc = 0.12751919968793342f;  // log2(e)/sqrt(128)
    float qe2 = (qe * c - qo * sn) * sc;
    float qo2 = (qe * sn + qo * c) * sc;
    Q[idx] = (u32)f2b(qe2) | ((u32)f2b(qo2) << 16);

    u32 kp = Kb[idx];
    float ke = b2f((u16)(kp & 0xffffu)), ko = b2f((u16)(kp >> 16));
    float ke2 = ke * c - ko * sn;
    float ko2 = ke * sn + ko * c;
    Kb[idx] = (u32)f2b(ke2) | ((u32)f2b(ko2) << 16);
}

// ---------------------------------------------------------------------------
// Causal flash attention v2.
//  - Pairing: block handles q-tiles (p, nt-1-p) -> exactly nt+1 KV-iters per
//    block, 512 blocks, perfect load balance (no causal tail).
//  - K tile: stride 128 elems + XOR swizzle col ^= (row&7)<<3  (write: lanes
//    span 256B contiguous -> free; read: banks spread -> ~2/bank).
//  - Vt ([d][kv], pad stride 72) + XOR swizzle kv ^= ((d>>3)&7)<<3 (write:
//    lane spread via d>>3 = lane&15; read: spread via 4*fr from the 72-pad).
//  - Q frags hoisted to regs (kt-invariant); Q-stage and O-transpose reuse Ks.
//  - T14 prefetch: next tile's K/V global->regs issued under current compute.
//  - Softmax: exp2-domain (log2e folded into Q), mask only diagonal tile,
//    rescale skipped when no lane's max grew (exact).
// ---------------------------------------------------------------------------
#define QT  64
#define KVT 64
#define VP  72
#define PP  72

__global__ __launch_bounds__(256) void attn_kernel(
    const u16* __restrict__ Qg, const u16* __restrict__ Kg, const u16* __restrict__ Vg,
    u16* __restrict__ Og, int S)
{
    __shared__ short Ks[64 * 128];     // 16 KB  K tile / Q stage / O transpose
    __shared__ short Vt[DK * VP];      // 18 KB  V^T: [d][kv] swizzled
    __shared__ short Ps[4][16 * PP];   //  9 KB  per-wave P: [q][kv]

    const int t    = threadIdx.x;
    const int lane = t & 63;
    const int w    = t >> 6;
    const int fr   = lane & 15;
    const int g4   = lane >> 4;
    const int xfr  = (fr & 7) << 3;    // frag-read XOR term (row&7 == fr&7)

    const int nt = S / QT;             // 32
    const int p  = blockIdx.x;         // pair id
    const int h  = blockIdx.y;
    const int b  = blockIdx.z;

    const size_t base = ((size_t)b * S) * D_MODEL + (size_t)h * DK;
    const u16* Qb = Qg + base;
    const u16* Kb = Kg + base;
    const u16* Vb = Vg + base;
    u16*       Ob = Og + base;

    // staging map: thread covers rows {row_base + 16c}, cols [c8, c8+8)
    const int row_base = t >> 4;               // 0..15
    const int c8       = (t & 15) * 8;         // 0..120
    const int kswz     = (row_base & 7) << 3;  // K/Q/O stage XOR (uniform in c)
    const int vswz     = ((c8 >> 3) & 7) << 3; // Vt write XOR (d>>3 == lane&15)

    const int qw = w * 16 + fr;                // this lane's local q row

    for (int half = 0; half < 2; half++) {
        const int qt  = half ? (nt - 1 - p) : p;
        const int q0  = qt * QT;
        const int nkv = qt + 1;

        // prefetch KV tile 0 into regs
        s8v kreg[4], vreg[4];
#pragma unroll
        for (int c = 0; c < 4; c++) {
            kreg[c] = *(const s8v*)(Kb + (size_t)(row_base + 16 * c) * D_MODEL + c8);
            vreg[c] = *(const s8v*)(Vb + (size_t)(row_base + 16 * c) * D_MODEL + c8);
        }

        // stage Q through Ks region (swizzled), hoist frags to regs
        __syncthreads();   // prev half's O-transpose reads done
#pragma unroll
        for (int c = 0; c < 4; c++) {
            s8v qv = *(const s8v*)(Qb + (size_t)(q0 + row_base + 16 * c) * D_MODEL + c8);
            *(s8v*)&Ks[(row_base + 16 * c) * 128 + (c8 ^ kswz)] = qv;
        }
        __syncthreads();
        s8v qf[4];
#pragma unroll
        for (int ks = 0; ks < 4; ks++)
            qf[ks] = *(const s8v*)&Ks[qw * 128 + ((ks * 32 + g4 * 8) ^ xfr)];

        float m_st = -1e30f, l_st = 0.f;
        f4v accO[8];
#pragma unroll
        for (int i = 0; i < 8; i++) accO[i] = (f4v){0.f, 0.f, 0.f, 0.f};
        const int q_g = q0 + qw;

        for (int kt = 0; kt < nkv; kt++) {
            __syncthreads();   // Ks/Vt safe to overwrite (Q-hoist / prev compute done)
            // write staged regs -> LDS (swizzled)
#pragma unroll
            for (int c = 0; c < 4; c++)
                *(s8v*)&Ks[(row_base + 16 * c) * 128 + (c8 ^ kswz)] = kreg[c];
#pragma unroll
            for (int c = 0; c < 4; c++) {
                int kvs = (row_base + 16 * c) ^ vswz;
#pragma unroll
                for (int j = 0; j < 8; j++)
                    Vt[(c8 + j) * VP + kvs] = vreg[c][j];
            }
            __syncthreads();

            // T14: issue next tile's loads under this tile's compute
            if (kt + 1 < nkv) {
                const size_t kv0n = (size_t)(kt + 1) * KVT;
#pragma unroll
                for (int c = 0; c < 4; c++) {
                    kreg[c] = *(const s8v*)(Kb + (kv0n + row_base + 16 * c) * D_MODEL + c8);
                    vreg[c] = *(const s8v*)(Vb + (kv0n + row_base + 16 * c) * D_MODEL + c8);
                }
            }

            // S^T = K * Q^T : C row = kv, col = q
            f4v sacc[4];
#pragma unroll
            for (int i = 0; i < 4; i++) sacc[i] = (f4v){0.f, 0.f, 0.f, 0.f};
#pragma unroll
            for (int ks = 0; ks < 4; ks++) {
#pragma unroll
                for (int kf = 0; kf < 4; kf++) {
                    s8v kfr = *(const s8v*)&Ks[(kf * 16 + fr) * 128 + ((ks * 32 + g4 * 8) ^ xfr)];
                    sacc[kf] = mfma16(kfr, qf[ks], sacc[kf]);
                }
            }

            // causal mask only on the diagonal tile (uniform branch)
            if (kt == qt) {
                const int kv0 = kt * KVT;
#pragma unroll
                for (int kf = 0; kf < 4; kf++)
#pragma unroll
                    for (int r = 0; r < 4; r++) {
                        int kv_g = kv0 + kf * 16 + g4 * 4 + r;
                        if (kv_g > q_g) sacc[kf][r] = -1e30f;
                    }
            }

            // online softmax in exp2 domain (per-lane q)
            float rowmax = -1e30f;
#pragma unroll
            for (int kf = 0; kf < 4; kf++) {
                rowmax = fmaxf(rowmax, fmaxf(fmaxf(sacc[kf][0], sacc[kf][1]),
                                             fmaxf(sacc[kf][2], sacc[kf][3])));
            }
            rowmax = fmaxf(rowmax, __shfl_xor(rowmax, 16));
            rowmax = fmaxf(rowmax, __shfl_xor(rowmax, 32));
            if (__any(rowmax > m_st)) {          // exact defer: P <= 1 otherwise
                float m_new = fmaxf(m_st, rowmax);
                float corr  = fexp2(m_st - m_new);
                l_st *= corr;
#pragma unroll
                for (int i = 0; i < 8; i++) {
                    accO[i][0] *= corr; accO[i][1] *= corr;
                    accO[i][2] *= corr; accO[i][3] *= corr;
                }
                m_st = m_new;
            }
            float rsum = 0.f;
#pragma unroll
            for (int kf = 0; kf < 4; kf++) {
                float p0 = fexp2(sacc[kf][0] - m_st);
                float p1 = fexp2(sacc[kf][1] - m_st);
                float p2 = fexp2(sacc[kf][2] - m_st);
                float p3 = fexp2(sacc[kf][3] - m_st);
                rsum += (p0 + p1) + (p2 + p3);
                s4v pk;
                pk[0] = (short)f2b(p0); pk[1] = (short)f2b(p1);
                pk[2] = (short)f2b(p2); pk[3] = (short)f2b(p3);
                *(s4v*)&Ps[w][fr * PP + kf * 16 + g4 * 4] = pk;
            }
            rsum += __shfl_xor(rsum, 16);
            rsum += __shfl_xor(rsum, 32);
            l_st += rsum;

            // O^T += V^T * P^T  (same-wave LDS RAW on Ps: DS pipe in-order)
#pragma unroll
            for (int ks = 0; ks < 2; ks++) {
                s8v pf = *(const s8v*)&Ps[w][fr * PP + ks * 32 + g4 * 8];
#pragma unroll
                for (int df = 0; df < 8; df++) {
                    int d   = df * 16 + fr;
                    int col = (ks * 32 + g4 * 8) ^ (((d >> 3) & 7) << 3);
                    s8v vf  = *(const s8v*)&Vt[d * VP + col];
                    accO[df] = mfma16(vf, pf, accO[df]);
                }
            }
        }

        // normalize, transpose O^T -> O through Ks region, coalesced store
        float inv = 1.f / l_st;
        __syncthreads();   // all waves done reading Ks/Vt
#pragma unroll
        for (int df = 0; df < 8; df++) {
            s4v ov;
            ov[0] = (short)f2b(accO[df][0] * inv);
            ov[1] = (short)f2b(accO[df][1] * inv);
            ov[2] = (short)f2b(accO[df][2] * inv);
            ov[3] = (short)f2b(accO[df][3] * inv);
            *(s4v*)&Ks[qw * 128 + ((df * 16 + g4 * 4) ^ xfr)] = ov;
        }
        __syncthreads();
#pragma unroll
        for (int c = 0; c < 4; c++) {
            int row = row_base + 16 * c;
            s8v v = *(const s8v*)&Ks[row * 128 + (c8 ^ kswz)];
            *(s8v*)(Ob + (size_t)(q0 + row) * D_MODEL + c8) = v;
        }
    }
}

// ---------------------------------------------------------------------------
extern "C" void kernel_launch(void* const* d_in, const int* in_sizes, int n_in,
                              void* d_out, int out_size, void* d_ws, size_t ws_size,
                              hipStream_t stream)
{
    const float* x  = (const float*)d_in[0];
    const float* wq = (const float*)d_in[1];
    const float* wk = (const float*)d_in[2];
    const float* wv = (const float*)d_in[3];
    const float* wo = (const float*)d_in[4];
    const int*   tp = (const int*)d_in[5];

    const int S  = in_sizes[5];
    const int BS = in_sizes[0] / D_MODEL;   // B*S rows (4096)
    const int Bn = BS / S;
    const int NW = D_MODEL * D_MODEL;
    const int NX = BS * D_MODEL;

    u16* Qw  = (u16*)d_ws;
    u16* Kw  = Qw + (size_t)NX;
    u16* Vw  = Kw + (size_t)NX;
    u16* Xb  = Vw + (size_t)NX;             // reused as attention output O
    u16* Wqb = Xb + (size_t)NX;
    u16* Wkb = Wqb + (size_t)NW;
    u16* Wvb = Wkb + (size_t)NW;
    u16* Wob = Wvb + (size_t)NW;

    {
        dim3 g((NX / 8 + 255) / 256, 5);
        cvt_bf16<<<g, 256, 0, stream>>>(x, wq, wk, wv, wo,
                                        Xb, Wqb, Wkb, Wvb, Wob, NX, NW);
    }

    dim3 gq(BS / 128, D_MODEL / 128, 3);
    gemm_bt3<u16><<<gq, 256, 0, stream>>>(Xb, Wqb, Wkb, Wvb, Qw, Kw, Vw,
                                          BS, D_MODEL, D_MODEL);

    int total = BS * (D_MODEL / 2);
    rope_kernel<<<(total + 255) / 256, 256, 0, stream>>>((u32*)Qw, (u32*)Kw, tp, total, S);

    dim3 ga(S / QT / 2, NH, Bn);            // paired q-tiles: 16 x 16 x 2 = 512 blocks
    attn_kernel<<<ga, 256, 0, stream>>>(Qw, Kw, Vw, Xb, S);

    dim3 go(BS / 128, D_MODEL / 128, 1);
    gemm_bt3<float><<<go, 256, 0, stream>>>(Xb, Wob, Wob, Wob,
                                            (float*)d_out, (float*)d_out, (float*)d_out,
                                            BS, D_MODEL, D_MODEL);
}

// Round 5
// 301.626 us; speedup vs baseline: 1.9001x; 1.1096x over previous
//
#include <hip/hip_runtime.h>
#include <stdint.h>
#include <stddef.h>

typedef unsigned short u16;
typedef unsigned int u32;
typedef __attribute__((ext_vector_type(8))) short s8v;   // 8 bf16 = one MFMA A/B frag
typedef __attribute__((ext_vector_type(4))) short s4v;
typedef __attribute__((ext_vector_type(4))) float f4v;   // MFMA C/D frag / float4

#define D_MODEL 2048
#define NH 16
#define DK 128

__device__ __forceinline__ float b2f(u16 u) {
    union { u32 i; float f; } v; v.i = ((u32)u) << 16; return v.f;
}
__device__ __forceinline__ u16 f2b(float f) {  // RNE; values here always finite
    u32 u = __builtin_bit_cast(u32, f);
    u32 r = (u + 0x7fffu + ((u >> 16) & 1u)) >> 16;
    return (u16)r;
}
__device__ __forceinline__ float fexp2(float x) {        // native v_exp_f32 (base-2)
    return __builtin_amdgcn_exp2f(x);
}
__device__ __forceinline__ f4v mfma16(s8v a, s8v b, f4v c) {
    return __builtin_amdgcn_mfma_f32_16x16x32_bf16(a, b, c, 0, 0, 0);
}
// async global->LDS, 16B/lane. LDS dest must be the WAVE-UNIFORM base; HW adds lane*16.
__device__ __forceinline__ void gload_lds16(const void* g, void* l) {
    __builtin_amdgcn_global_load_lds(
        (const __attribute__((address_space(1))) u32*)(uintptr_t)g,
        (__attribute__((address_space(3))) u32*)(uintptr_t)l, 16, 0, 0);
}

__device__ __forceinline__ void store_out(u16* p, float v)   { *p = f2b(v); }
__device__ __forceinline__ void store_out(float* p, float v) { *p = v; }

// ---------------------------------------------------------------------------
// fp32 -> bf16 conversion pass. grid.y selects segment (0: x, 1..4: weights).
// ---------------------------------------------------------------------------
__global__ __launch_bounds__(256) void cvt_bf16(
    const float* __restrict__ s0, const float* __restrict__ s1,
    const float* __restrict__ s2, const float* __restrict__ s3,
    const float* __restrict__ s4,
    u16* __restrict__ d0, u16* __restrict__ d1, u16* __restrict__ d2,
    u16* __restrict__ d3, u16* __restrict__ d4,
    int n0, int nw)
{
    const int seg = blockIdx.y;
    const float* s = (seg == 0) ? s0 : (seg == 1) ? s1 : (seg == 2) ? s2 : (seg == 3) ? s3 : s4;
    u16*         d = (seg == 0) ? d0 : (seg == 1) ? d1 : (seg == 2) ? d2 : (seg == 3) ? d3 : d4;
    const int    n = (seg == 0) ? n0 : nw;
    int i = (blockIdx.x * 256 + threadIdx.x) * 8;
    if (i >= n) return;
    f4v a = *(const f4v*)(s + i);
    f4v b = *(const f4v*)(s + i + 4);
    s8v o;
    o[0] = (short)f2b(a[0]); o[1] = (short)f2b(a[1]);
    o[2] = (short)f2b(a[2]); o[3] = (short)f2b(a[3]);
    o[4] = (short)f2b(b[0]); o[5] = (short)f2b(b[1]);
    o[6] = (short)f2b(b[2]); o[7] = (short)f2b(b[3]);
    *(s8v*)(d + i) = o;
}

// ---------------------------------------------------------------------------
// GEMM: C[M,N] = A[M,K] * B^T (B given [N,K] row-major). 128x128 tile, BK=64,
// 4 waves of 64x64. T2 XOR swizzle with LINEAR LDS (global_load_lds writes
// base+lane*16): the per-lane GLOBAL source column carries the involution
// blk ^= (row&7); frag reads apply the same XOR -> uniform bank spread
// (8 lanes per 16B slot x 8 slots = all 32 banks; b128 minimum cycles).
// grid.z selects (B,C) pair so QKV is one launch. OutT = u16 (bf16) or float.
// ---------------------------------------------------------------------------
template<typename OutT>
__global__ __launch_bounds__(256) void gemm_bt3(
    const u16* __restrict__ A,
    const u16* __restrict__ B0, const u16* __restrict__ B1, const u16* __restrict__ B2,
    OutT* __restrict__ C0, OutT* __restrict__ C1, OutT* __restrict__ C2,
    int M, int N, int K)
{
    const int z = blockIdx.z;
    const u16* Bp = (z == 0) ? B0 : (z == 1) ? B1 : B2;
    OutT*      Cp = (z == 0) ? C0 : (z == 1) ? C1 : C2;

    __shared__ short As[128 * 64];   // [row][k] 16 KB, linear (swizzle is in data)
    __shared__ short Bs[128 * 64];

    const int t    = threadIdx.x;
    const int lane = t & 63;
    const int w    = t >> 6;
    const int wm   = (w >> 1) * 64;
    const int wn   = (w & 1) * 64;
    const int m0   = blockIdx.x * 128;
    const int n0   = blockIdx.y * 128;

    // staging map (issue i): LDS row = i*32 + (t>>3), LDS blk = t&7 (linear);
    // data fetched from global blk = (t&7) ^ (row&7)  [row&7 == (t>>3)&7]
    const int srow = t >> 3;                         // 0..31
    const int scol = (((t & 7) ^ ((t >> 3) & 7)) * 8);

    f4v acc[4][4];
#pragma unroll
    for (int i = 0; i < 4; i++)
#pragma unroll
        for (int j = 0; j < 4; j++) acc[i][j] = (f4v){0.f, 0.f, 0.f, 0.f};

    const u16* gA = A  + (size_t)(m0 + srow) * K + scol;
    const u16* gB = Bp + (size_t)(n0 + srow) * K + scol;
    char* lA = (char*)As + (size_t)w * 1024;   // wave-uniform LDS bases
    char* lB = (char*)Bs + (size_t)w * 1024;

    const int fr = lane & 15;
    const int g4 = lane >> 4;
    const int xa = fr & 7;                     // read-side XOR term (row&7)

    const size_t rstep = (size_t)32 * K;

    for (int kt = 0; kt < K; kt += 64) {
        __syncthreads();                         // prev compute done reading LDS
#pragma unroll
        for (int i = 0; i < 4; i++)
            gload_lds16(gA + (size_t)i * rstep + kt, lA + i * 4096);
#pragma unroll
        for (int i = 0; i < 4; i++)
            gload_lds16(gB + (size_t)i * rstep + kt, lB + i * 4096);
        __syncthreads();                         // compiler drains vmcnt(0) before barrier

#pragma unroll
        for (int ks = 0; ks < 2; ks++) {
            s8v aF[4], bF[4];
#pragma unroll
            for (int mi = 0; mi < 4; mi++)
                aF[mi] = *(const s8v*)&As[(wm + mi * 16 + fr) * 64 +
                                          (((ks * 4 + g4) ^ xa) * 8)];
#pragma unroll
            for (int ni = 0; ni < 4; ni++)
                bF[ni] = *(const s8v*)&Bs[(wn + ni * 16 + fr) * 64 +
                                          (((ks * 4 + g4) ^ xa) * 8)];
#pragma unroll
            for (int mi = 0; mi < 4; mi++)
#pragma unroll
                for (int ni = 0; ni < 4; ni++)
                    acc[mi][ni] = mfma16(aF[mi], bF[ni], acc[mi][ni]);
        }
    }

    // epilogue: C row = (lane>>4)*4+reg, col = lane&15  (m89-verified layout)
    const int rg = (lane >> 4) * 4;
#pragma unroll
    for (int mi = 0; mi < 4; mi++)
#pragma unroll
        for (int ni = 0; ni < 4; ni++) {
            size_t base = (size_t)(m0 + wm + mi * 16 + rg) * N + (n0 + wn + ni * 16 + fr);
#pragma unroll
            for (int r = 0; r < 4; r++)
                store_out(&Cp[base + (size_t)r * N], acc[mi][ni][r]);
        }
}

// ---------------------------------------------------------------------------
// RoPE in-place on Q and K. Folds (1/sqrt(DK))*log2(e) into Q so attention
// softmax can use exp2 directly.
// ---------------------------------------------------------------------------
__global__ void rope_kernel(u32* __restrict__ Q, u32* __restrict__ Kb,
                            const int* __restrict__ pos, int total, int S)
{
    int idx = blockIdx.x * 256 + threadIdx.x;
    if (idx >= total) return;
    int row = idx >> 10;            // 1024 pairs per row
    int pr  = idx & 1023;
    int i   = pr & 63;              // pair index within head
    int s   = row % S;
    float p    = (float)pos[s];
    float freq = __expf((float)i * -0.14391156831212787f);  // 10000^(-i/64)
    float ang  = p * freq;
    float c = cosf(ang), sn = sinf(ang);

    u32 qp = Q[idx];
    float qe = b2f((u16)(qp & 0xffffu)), qo = b2f((u16)(qp >> 16));
    const float sc = 0.12751919968793342f;  // log2(e)/sqrt(128)
    float qe2 = (qe * c - qo * sn) * sc;
    float qo2 = (qe * sn + qo * c) * sc;
    Q[idx] = (u32)f2b(qe2) | ((u32)f2b(qo2) << 16);

    u32 kp = Kb[idx];
    float ke = b2f((u16)(kp & 0xffffu)), ko = b2f((u16)(kp >> 16));
    float ke2 = ke * c - ko * sn;
    float ko2 = ke * sn + ko * c;
    Kb[idx] = (u32)f2b(ke2) | ((u32)f2b(ko2) << 16);
}

// ---------------------------------------------------------------------------
// Causal flash attention v2 (unchanged from round 4).
// ---------------------------------------------------------------------------
#define QT  64
#define KVT 64
#define VP  72
#define PP  72

__global__ __launch_bounds__(256) void attn_kernel(
    const u16* __restrict__ Qg, const u16* __restrict__ Kg, const u16* __restrict__ Vg,
    u16* __restrict__ Og, int S)
{
    __shared__ short Ks[64 * 128];     // 16 KB  K tile / Q stage / O transpose
    __shared__ short Vt[DK * VP];      // 18 KB  V^T: [d][kv] swizzled
    __shared__ short Ps[4][16 * PP];   //  9 KB  per-wave P: [q][kv]

    const int t    = threadIdx.x;
    const int lane = t & 63;
    const int w    = t >> 6;
    const int fr   = lane & 15;
    const int g4   = lane >> 4;
    const int xfr  = (fr & 7) << 3;    // frag-read XOR term (row&7 == fr&7)

    const int nt = S / QT;             // 32
    const int p  = blockIdx.x;         // pair id
    const int h  = blockIdx.y;
    const int b  = blockIdx.z;

    const size_t base = ((size_t)b * S) * D_MODEL + (size_t)h * DK;
    const u16* Qb = Qg + base;
    const u16* Kb = Kg + base;
    const u16* Vb = Vg + base;
    u16*       Ob = Og + base;

    // staging map: thread covers rows {row_base + 16c}, cols [c8, c8+8)
    const int row_base = t >> 4;               // 0..15
    const int c8       = (t & 15) * 8;         // 0..120
    const int kswz     = (row_base & 7) << 3;  // K/Q/O stage XOR (uniform in c)
    const int vswz     = ((c8 >> 3) & 7) << 3; // Vt write XOR (d>>3 == lane&15)

    const int qw = w * 16 + fr;                // this lane's local q row

    for (int half = 0; half < 2; half++) {
        const int qt  = half ? (nt - 1 - p) : p;
        const int q0  = qt * QT;
        const int nkv = qt + 1;

        // prefetch KV tile 0 into regs
        s8v kreg[4], vreg[4];
#pragma unroll
        for (int c = 0; c < 4; c++) {
            kreg[c] = *(const s8v*)(Kb + (size_t)(row_base + 16 * c) * D_MODEL + c8);
            vreg[c] = *(const s8v*)(Vb + (size_t)(row_base + 16 * c) * D_MODEL + c8);
        }

        // stage Q through Ks region (swizzled), hoist frags to regs
        __syncthreads();   // prev half's O-transpose reads done
#pragma unroll
        for (int c = 0; c < 4; c++) {
            s8v qv = *(const s8v*)(Qb + (size_t)(q0 + row_base + 16 * c) * D_MODEL + c8);
            *(s8v*)&Ks[(row_base + 16 * c) * 128 + (c8 ^ kswz)] = qv;
        }
        __syncthreads();
        s8v qf[4];
#pragma unroll
        for (int ks = 0; ks < 4; ks++)
            qf[ks] = *(const s8v*)&Ks[qw * 128 + ((ks * 32 + g4 * 8) ^ xfr)];

        float m_st = -1e30f, l_st = 0.f;
        f4v accO[8];
#pragma unroll
        for (int i = 0; i < 8; i++) accO[i] = (f4v){0.f, 0.f, 0.f, 0.f};
        const int q_g = q0 + qw;

        for (int kt = 0; kt < nkv; kt++) {
            __syncthreads();   // Ks/Vt safe to overwrite (Q-hoist / prev compute done)
            // write staged regs -> LDS (swizzled)
#pragma unroll
            for (int c = 0; c < 4; c++)
                *(s8v*)&Ks[(row_base + 16 * c) * 128 + (c8 ^ kswz)] = kreg[c];
#pragma unroll
            for (int c = 0; c < 4; c++) {
                int kvs = (row_base + 16 * c) ^ vswz;
#pragma unroll
                for (int j = 0; j < 8; j++)
                    Vt[(c8 + j) * VP + kvs] = vreg[c][j];
            }
            __syncthreads();

            // T14: issue next tile's loads under this tile's compute
            if (kt + 1 < nkv) {
                const size_t kv0n = (size_t)(kt + 1) * KVT;
#pragma unroll
                for (int c = 0; c < 4; c++) {
                    kreg[c] = *(const s8v*)(Kb + (kv0n + row_base + 16 * c) * D_MODEL + c8);
                    vreg[c] = *(const s8v*)(Vb + (kv0n + row_base + 16 * c) * D_MODEL + c8);
                }
            }

            // S^T = K * Q^T : C row = kv, col = q
            f4v sacc[4];
#pragma unroll
            for (int i = 0; i < 4; i++) sacc[i] = (f4v){0.f, 0.f, 0.f, 0.f};
#pragma unroll
            for (int ks = 0; ks < 4; ks++) {
#pragma unroll
                for (int kf = 0; kf < 4; kf++) {
                    s8v kfr = *(const s8v*)&Ks[(kf * 16 + fr) * 128 + ((ks * 32 + g4 * 8) ^ xfr)];
                    sacc[kf] = mfma16(kfr, qf[ks], sacc[kf]);
                }
            }

            // causal mask only on the diagonal tile (uniform branch)
            if (kt == qt) {
                const int kv0 = kt * KVT;
#pragma unroll
                for (int kf = 0; kf < 4; kf++)
#pragma unroll
                    for (int r = 0; r < 4; r++) {
                        int kv_g = kv0 + kf * 16 + g4 * 4 + r;
                        if (kv_g > q_g) sacc[kf][r] = -1e30f;
                    }
            }

            // online softmax in exp2 domain (per-lane q)
            float rowmax = -1e30f;
#pragma unroll
            for (int kf = 0; kf < 4; kf++) {
                rowmax = fmaxf(rowmax, fmaxf(fmaxf(sacc[kf][0], sacc[kf][1]),
                                             fmaxf(sacc[kf][2], sacc[kf][3])));
            }
            rowmax = fmaxf(rowmax, __shfl_xor(rowmax, 16));
            rowmax = fmaxf(rowmax, __shfl_xor(rowmax, 32));
            if (__any(rowmax > m_st)) {          // exact defer: P <= 1 otherwise
                float m_new = fmaxf(m_st, rowmax);
                float corr  = fexp2(m_st - m_new);
                l_st *= corr;
#pragma unroll
                for (int i = 0; i < 8; i++) {
                    accO[i][0] *= corr; accO[i][1] *= corr;
                    accO[i][2] *= corr; accO[i][3] *= corr;
                }
                m_st = m_new;
            }
            float rsum = 0.f;
#pragma unroll
            for (int kf = 0; kf < 4; kf++) {
                float p0 = fexp2(sacc[kf][0] - m_st);
                float p1 = fexp2(sacc[kf][1] - m_st);
                float p2 = fexp2(sacc[kf][2] - m_st);
                float p3 = fexp2(sacc[kf][3] - m_st);
                rsum += (p0 + p1) + (p2 + p3);
                s4v pk;
                pk[0] = (short)f2b(p0); pk[1] = (short)f2b(p1);
                pk[2] = (short)f2b(p2); pk[3] = (short)f2b(p3);
                *(s4v*)&Ps[w][fr * PP + kf * 16 + g4 * 4] = pk;
            }
            rsum += __shfl_xor(rsum, 16);
            rsum += __shfl_xor(rsum, 32);
            l_st += rsum;

            // O^T += V^T * P^T  (same-wave LDS RAW on Ps: DS pipe in-order)
#pragma unroll
            for (int ks = 0; ks < 2; ks++) {
                s8v pf = *(const s8v*)&Ps[w][fr * PP + ks * 32 + g4 * 8];
#pragma unroll
                for (int df = 0; df < 8; df++) {
                    int d   = df * 16 + fr;
                    int col = (ks * 32 + g4 * 8) ^ (((d >> 3) & 7) << 3);
                    s8v vf  = *(const s8v*)&Vt[d * VP + col];
                    accO[df] = mfma16(vf, pf, accO[df]);
                }
            }
        }

        // normalize, transpose O^T -> O through Ks region, coalesced store
        float inv = 1.f / l_st;
        __syncthreads();   // all waves done reading Ks/Vt
#pragma unroll
        for (int df = 0; df < 8; df++) {
            s4v ov;
            ov[0] = (short)f2b(accO[df][0] * inv);
            ov[1] = (short)f2b(accO[df][1] * inv);
            ov[2] = (short)f2b(accO[df][2] * inv);
            ov[3] = (short)f2b(accO[df][3] * inv);
            *(s4v*)&Ks[qw * 128 + ((df * 16 + g4 * 4) ^ xfr)] = ov;
        }
        __syncthreads();
#pragma unroll
        for (int c = 0; c < 4; c++) {
            int row = row_base + 16 * c;
            s8v v = *(const s8v*)&Ks[row * 128 + (c8 ^ kswz)];
            *(s8v*)(Ob + (size_t)(q0 + row) * D_MODEL + c8) = v;
        }
    }
}

// ---------------------------------------------------------------------------
extern "C" void kernel_launch(void* const* d_in, const int* in_sizes, int n_in,
                              void* d_out, int out_size, void* d_ws, size_t ws_size,
                              hipStream_t stream)
{
    const float* x  = (const float*)d_in[0];
    const float* wq = (const float*)d_in[1];
    const float* wk = (const float*)d_in[2];
    const float* wv = (const float*)d_in[3];
    const float* wo = (const float*)d_in[4];
    const int*   tp = (const int*)d_in[5];

    const int S  = in_sizes[5];
    const int BS = in_sizes[0] / D_MODEL;   // B*S rows (4096)
    const int Bn = BS / S;
    const int NW = D_MODEL * D_MODEL;
    const int NX = BS * D_MODEL;

    u16* Qw  = (u16*)d_ws;
    u16* Kw  = Qw + (size_t)NX;
    u16* Vw  = Kw + (size_t)NX;
    u16* Xb  = Vw + (size_t)NX;             // reused as attention output O
    u16* Wqb = Xb + (size_t)NX;
    u16* Wkb = Wqb + (size_t)NW;
    u16* Wvb = Wkb + (size_t)NW;
    u16* Wob = Wvb + (size_t)NW;

    {
        dim3 g((NX / 8 + 255) / 256, 5);
        cvt_bf16<<<g, 256, 0, stream>>>(x, wq, wk, wv, wo,
                                        Xb, Wqb, Wkb, Wvb, Wob, NX, NW);
    }

    dim3 gq(BS / 128, D_MODEL / 128, 3);
    gemm_bt3<u16><<<gq, 256, 0, stream>>>(Xb, Wqb, Wkb, Wvb, Qw, Kw, Vw,
                                          BS, D_MODEL, D_MODEL);

    int total = BS * (D_MODEL / 2);
    rope_kernel<<<(total + 255) / 256, 256, 0, stream>>>((u32*)Qw, (u32*)Kw, tp, total, S);

    dim3 ga(S / QT / 2, NH, Bn);            // paired q-tiles: 16 x 16 x 2 = 512 blocks
    attn_kernel<<<ga, 256, 0, stream>>>(Qw, Kw, Vw, Xb, S);

    dim3 go(BS / 128, D_MODEL / 128, 1);
    gemm_bt3<float><<<go, 256, 0, stream>>>(Xb, Wob, Wob, Wob,
                                            (float*)d_out, (float*)d_out, (float*)d_out,
                                            BS, D_MODEL, D_MODEL);
}

// Round 6
// 292.683 us; speedup vs baseline: 1.9582x; 1.0306x over previous
//
#include <hip/hip_runtime.h>
#include <stdint.h>
#include <stddef.h>

typedef unsigned short u16;
typedef unsigned int u32;
typedef __attribute__((ext_vector_type(8))) short s8v;   // 8 bf16 = one MFMA A/B frag
typedef __attribute__((ext_vector_type(4))) short s4v;
typedef __attribute__((ext_vector_type(4))) float f4v;   // MFMA C/D frag / float4

#define D_MODEL 2048
#define NH 16
#define DK 128

__device__ __forceinline__ float b2f(u16 u) {
    union { u32 i; float f; } v; v.i = ((u32)u) << 16; return v.f;
}
__device__ __forceinline__ u16 f2b(float f) {  // RNE; values here always finite
    u32 u = __builtin_bit_cast(u32, f);
    u32 r = (u + 0x7fffu + ((u >> 16) & 1u)) >> 16;
    return (u16)r;
}
__device__ __forceinline__ float fexp2(float x) {        // native v_exp_f32 (base-2)
    return __builtin_amdgcn_exp2f(x);
}
__device__ __forceinline__ f4v mfma16(s8v a, s8v b, f4v c) {
    return __builtin_amdgcn_mfma_f32_16x16x32_bf16(a, b, c, 0, 0, 0);
}
// async global->LDS, 16B/lane. LDS dest must be the WAVE-UNIFORM base; HW adds lane*16.
__device__ __forceinline__ void gload_lds16(const void* g, void* l) {
    __builtin_amdgcn_global_load_lds(
        (const __attribute__((address_space(1))) u32*)(uintptr_t)g,
        (__attribute__((address_space(3))) u32*)(uintptr_t)l, 16, 0, 0);
}

__device__ __forceinline__ void store_out(u16* p, float v)   { *p = f2b(v); }
__device__ __forceinline__ void store_out(float* p, float v) { *p = v; }

// ---------------------------------------------------------------------------
// fp32 -> bf16 conversion pass. grid.y selects segment (0: x, 1..4: weights).
// ---------------------------------------------------------------------------
__global__ __launch_bounds__(256) void cvt_bf16(
    const float* __restrict__ s0, const float* __restrict__ s1,
    const float* __restrict__ s2, const float* __restrict__ s3,
    const float* __restrict__ s4,
    u16* __restrict__ d0, u16* __restrict__ d1, u16* __restrict__ d2,
    u16* __restrict__ d3, u16* __restrict__ d4,
    int n0, int nw)
{
    const int seg = blockIdx.y;
    const float* s = (seg == 0) ? s0 : (seg == 1) ? s1 : (seg == 2) ? s2 : (seg == 3) ? s3 : s4;
    u16*         d = (seg == 0) ? d0 : (seg == 1) ? d1 : (seg == 2) ? d2 : (seg == 3) ? d3 : d4;
    const int    n = (seg == 0) ? n0 : nw;
    int i = (blockIdx.x * 256 + threadIdx.x) * 8;
    if (i >= n) return;
    f4v a = *(const f4v*)(s + i);
    f4v b = *(const f4v*)(s + i + 4);
    s8v o;
    o[0] = (short)f2b(a[0]); o[1] = (short)f2b(a[1]);
    o[2] = (short)f2b(a[2]); o[3] = (short)f2b(a[3]);
    o[4] = (short)f2b(b[0]); o[5] = (short)f2b(b[1]);
    o[6] = (short)f2b(b[2]); o[7] = (short)f2b(b[3]);
    *(s8v*)(d + i) = o;
}

// ---------------------------------------------------------------------------
// GEMM: C[M,N] = A[M,K] * B^T (B given [N,K] row-major). 128x128 tile, BK=64,
// 4 waves of 64x64, T2 XOR swizzle via pre-swizzled global source + swizzled
// frag reads (LDS stays linear for global_load_lds). Unchanged from round 5.
// ---------------------------------------------------------------------------
template<typename OutT>
__global__ __launch_bounds__(256) void gemm_bt3(
    const u16* __restrict__ A,
    const u16* __restrict__ B0, const u16* __restrict__ B1, const u16* __restrict__ B2,
    OutT* __restrict__ C0, OutT* __restrict__ C1, OutT* __restrict__ C2,
    int M, int N, int K)
{
    const int z = blockIdx.z;
    const u16* Bp = (z == 0) ? B0 : (z == 1) ? B1 : B2;
    OutT*      Cp = (z == 0) ? C0 : (z == 1) ? C1 : C2;

    __shared__ short As[128 * 64];   // [row][k] 16 KB, linear (swizzle is in data)
    __shared__ short Bs[128 * 64];

    const int t    = threadIdx.x;
    const int lane = t & 63;
    const int w    = t >> 6;
    const int wm   = (w >> 1) * 64;
    const int wn   = (w & 1) * 64;
    const int m0   = blockIdx.x * 128;
    const int n0   = blockIdx.y * 128;

    const int srow = t >> 3;                         // 0..31
    const int scol = (((t & 7) ^ ((t >> 3) & 7)) * 8);

    f4v acc[4][4];
#pragma unroll
    for (int i = 0; i < 4; i++)
#pragma unroll
        for (int j = 0; j < 4; j++) acc[i][j] = (f4v){0.f, 0.f, 0.f, 0.f};

    const u16* gA = A  + (size_t)(m0 + srow) * K + scol;
    const u16* gB = Bp + (size_t)(n0 + srow) * K + scol;
    char* lA = (char*)As + (size_t)w * 1024;   // wave-uniform LDS bases
    char* lB = (char*)Bs + (size_t)w * 1024;

    const int fr = lane & 15;
    const int g4 = lane >> 4;
    const int xa = fr & 7;                     // read-side XOR term (row&7)

    const size_t rstep = (size_t)32 * K;

    for (int kt = 0; kt < K; kt += 64) {
        __syncthreads();
#pragma unroll
        for (int i = 0; i < 4; i++)
            gload_lds16(gA + (size_t)i * rstep + kt, lA + i * 4096);
#pragma unroll
        for (int i = 0; i < 4; i++)
            gload_lds16(gB + (size_t)i * rstep + kt, lB + i * 4096);
        __syncthreads();

#pragma unroll
        for (int ks = 0; ks < 2; ks++) {
            s8v aF[4], bF[4];
#pragma unroll
            for (int mi = 0; mi < 4; mi++)
                aF[mi] = *(const s8v*)&As[(wm + mi * 16 + fr) * 64 +
                                          (((ks * 4 + g4) ^ xa) * 8)];
#pragma unroll
            for (int ni = 0; ni < 4; ni++)
                bF[ni] = *(const s8v*)&Bs[(wn + ni * 16 + fr) * 64 +
                                          (((ks * 4 + g4) ^ xa) * 8)];
#pragma unroll
            for (int mi = 0; mi < 4; mi++)
#pragma unroll
                for (int ni = 0; ni < 4; ni++)
                    acc[mi][ni] = mfma16(aF[mi], bF[ni], acc[mi][ni]);
        }
    }

    const int rg = (lane >> 4) * 4;
#pragma unroll
    for (int mi = 0; mi < 4; mi++)
#pragma unroll
        for (int ni = 0; ni < 4; ni++) {
            size_t base = (size_t)(m0 + wm + mi * 16 + rg) * N + (n0 + wn + ni * 16 + fr);
#pragma unroll
            for (int r = 0; r < 4; r++)
                store_out(&Cp[base + (size_t)r * N], acc[mi][ni][r]);
        }
}

// ---------------------------------------------------------------------------
// RoPE in-place on Q and K. Folds (1/sqrt(DK))*log2(e) into Q so attention
// softmax can use exp2 directly.
// ---------------------------------------------------------------------------
__global__ void rope_kernel(u32* __restrict__ Q, u32* __restrict__ Kb,
                            const int* __restrict__ pos, int total, int S)
{
    int idx = blockIdx.x * 256 + threadIdx.x;
    if (idx >= total) return;
    int row = idx >> 10;            // 1024 pairs per row
    int pr  = idx & 1023;
    int i   = pr & 63;              // pair index within head
    int s   = row % S;
    float p    = (float)pos[s];
    float freq = __expf((float)i * -0.14391156831212787f);  // 10000^(-i/64)
    float ang  = p * freq;
    float c = cosf(ang), sn = sinf(ang);

    u32 qp = Q[idx];
    float qe = b2f((u16)(qp & 0xffffu)), qo = b2f((u16)(qp >> 16));
    const float sc = 0.12751919968793342f;  // log2(e)/sqrt(128)
    float qe2 = (qe * c - qo * sn) * sc;
    float qo2 = (qe * sn + qo * c) * sc;
    Q[idx] = (u32)f2b(qe2) | ((u32)f2b(qo2) << 16);

    u32 kp = Kb[idx];
    float ke = b2f((u16)(kp & 0xffffu)), ko = b2f((u16)(kp >> 16));
    float ke2 = ke * c - ko * sn;
    float ko2 = ke * sn + ko * c;
    Kb[idx] = (u32)f2b(ke2) | ((u32)f2b(ko2) << 16);
}

// ---------------------------------------------------------------------------
// V transpose: V [b*S + s][o] -> Vt [b][o][s]  (per-batch 2048x2048 transpose)
// so attention can stage V^T tiles with b128 writes instead of 32 b16 scalars.
// ---------------------------------------------------------------------------
__global__ __launch_bounds__(256) void transpose_v(
    const u16* __restrict__ V, u16* __restrict__ Vt, int S)
{
    __shared__ short Tl[64 * 72];
    const int t  = threadIdx.x;
    const int s0 = blockIdx.x * 64;
    const int o0 = blockIdx.y * 64;
    const int b  = blockIdx.z;
    const int r  = t >> 3;            // 0..31
    const int c8 = (t & 7) * 8;
#pragma unroll
    for (int i = 0; i < 2; i++) {
        int row = r + i * 32;         // s within tile
        *(s8v*)&Tl[row * 72 + c8] =
            *(const s8v*)(V + ((size_t)b * S + s0 + row) * D_MODEL + o0 + c8);
    }
    __syncthreads();
#pragma unroll
    for (int i = 0; i < 2; i++) {
        int orow = r + i * 32;        // o within tile
        s8v v;
#pragma unroll
        for (int j = 0; j < 8; j++)
            v[j] = Tl[(c8 + j) * 72 + orow];
        *(s8v*)(Vt + ((size_t)b * D_MODEL + o0 + orow) * S + s0 + c8) = v;
    }
}

// ---------------------------------------------------------------------------
// Causal flash attention v3.
//  - 128 q rows/block, 4 waves x 32 q (2 subtiles of 16): each K/V A-frag
//    read feeds 2 MFMA -> DS reads per MFMA halved vs v2.
//  - V^T pre-transposed globally: staging is 4 b128 writes (was 32 b16).
//  - Double-buffered K/V LDS + T14 reg prefetch: ONE barrier per KV-iter.
//  - Pairing (T, 15-T): every block exactly 34 iters; 256 blocks = 1/CU.
//  - XCD-bijective decode: all 8 pair-blocks of one (b,h) on one XCD
//    (KV working set 4MB = one L2).
//  - Swapped QK^T (lane owns one q), exp2-domain softmax, diag-only mask,
//    rescale skip; O transposed through LDS (Kbuf reuse) for coalesced store.
// ---------------------------------------------------------------------------
#define AKV 64
#define VP  72
#define PP  72

__global__ __launch_bounds__(256) void attn_kernel(
    const u16* __restrict__ Qg, const u16* __restrict__ Kg,
    const u16* __restrict__ Vtg, u16* __restrict__ Og, int S)
{
    __shared__ short Kbuf[2][64 * 128];    // 32 KB (also O[128][128] staging)
    __shared__ short Vbuf[2][128 * VP];    // 36 KB  V^T tiles [d][kv]
    __shared__ short Ps[4][32 * PP];       // 18 KB  per-wave P [q][kv]

    const int t    = threadIdx.x;
    const int lane = t & 63;
    const int w    = t >> 6;
    const int fr   = lane & 15;
    const int g4   = lane >> 4;
    const int xfr  = (fr & 7) << 3;

    // XCD-bijective decode (grid.x = 256 = 8 pairs x 32 (b,h) groups):
    // dispatch d = (G&7) + 8*((G>>3) + 4*p)  ->  xcd = d%8 = G%8
    const int d_ = blockIdx.x;
    const int tt = d_ >> 3;
    const int G  = ((tt & 3) << 3) | (d_ & 7);
    const int p  = tt >> 2;
    const int h  = G & 15;
    const int b  = G >> 4;
    const int ntq = S / 128;               // 16

    const u16* Qb  = Qg + ((size_t)b * S) * D_MODEL + (size_t)h * DK;
    const u16* Kb  = Kg + ((size_t)b * S) * D_MODEL + (size_t)h * DK;
    const u16* Vtb = Vtg + ((size_t)b * D_MODEL + (size_t)h * DK) * S;
    u16*       Ob  = Og + ((size_t)b * S) * D_MODEL + (size_t)h * DK;

    // staging maps
    const int krow = t >> 4;               // K tile row base (0..15, +16c)
    const int kc8  = (t & 15) * 8;
    const int kxor = (krow & 7) << 3;
    const int vd   = t >> 3;               // V^T tile d base (0..31, +32c)
    const int vk8  = (t & 7) * 8;

    for (int half = 0; half < 2; half++) {
        const int T   = half ? (ntq - 1 - p) : p;
        const int q0  = T * 128;
        const int nkv = 2 * T + 2;

        // Q frags direct from global (once per half)
        s8v qf[2][4];
#pragma unroll
        for (int s = 0; s < 2; s++)
#pragma unroll
            for (int ks = 0; ks < 4; ks++)
                qf[s][ks] = *(const s8v*)(Qb +
                    (size_t)(q0 + s * 64 + w * 16 + fr) * D_MODEL + ks * 32 + g4 * 8);

        // tile 0 -> regs
        s8v kreg[4], vreg[4];
#pragma unroll
        for (int c = 0; c < 4; c++) {
            kreg[c] = *(const s8v*)(Kb + (size_t)(krow + 16 * c) * D_MODEL + kc8);
            vreg[c] = *(const s8v*)(Vtb + (size_t)(32 * c + vd) * S + vk8);
        }
        __syncthreads();                   // prev half's O-staging reads done
#pragma unroll
        for (int c = 0; c < 4; c++)
            *(s8v*)&Kbuf[0][(krow + 16 * c) * 128 + (kc8 ^ kxor)] = kreg[c];
#pragma unroll
        for (int c = 0; c < 4; c++)
            *(s8v*)&Vbuf[0][(32 * c + vd) * VP + vk8] = vreg[c];
        __syncthreads();

        float m_st[2] = {-1e30f, -1e30f};
        float l_st[2] = {0.f, 0.f};
        f4v accO[2][8];
#pragma unroll
        for (int s = 0; s < 2; s++)
#pragma unroll
            for (int df = 0; df < 8; df++) accO[s][df] = (f4v){0.f, 0.f, 0.f, 0.f};

        for (int kt = 0; kt < nkv; kt++) {
            const int  kv0  = kt * AKV;
            const int  buf  = kt & 1;
            const bool last = (kt + 1 == nkv);
            const bool do0  = (kv0 < q0 + 64);   // sub0 has any unmasked kv

            // T14: issue next tile's global loads now, consume after compute
            if (!last) {
                const size_t kvn = (size_t)(kt + 1) * AKV;
#pragma unroll
                for (int c = 0; c < 4; c++) {
                    kreg[c] = *(const s8v*)(Kb + (kvn + krow + 16 * c) * D_MODEL + kc8);
                    vreg[c] = *(const s8v*)(Vtb + (size_t)(32 * c + vd) * S + kvn + vk8);
                }
            }

            // S^T = K * Q^T for both q-subtiles (shared kfr)
            f4v sacc[2][4];
#pragma unroll
            for (int s = 0; s < 2; s++)
#pragma unroll
                for (int i = 0; i < 4; i++) sacc[s][i] = (f4v){0.f, 0.f, 0.f, 0.f};
#pragma unroll
            for (int ks = 0; ks < 4; ks++) {
                s8v kfr[4];
#pragma unroll
                for (int kf = 0; kf < 4; kf++)
                    kfr[kf] = *(const s8v*)&Kbuf[buf][(kf * 16 + fr) * 128 +
                                                     ((ks * 32 + g4 * 8) ^ xfr)];
                if (do0) {
#pragma unroll
                    for (int kf = 0; kf < 4; kf++)
                        sacc[0][kf] = mfma16(kfr[kf], qf[0][ks], sacc[0][kf]);
                }
#pragma unroll
                for (int kf = 0; kf < 4; kf++)
                    sacc[1][kf] = mfma16(kfr[kf], qf[1][ks], sacc[1][kf]);
            }

            // per-sub online softmax (exp2 domain; per-lane q = fr)
#pragma unroll
            for (int s = 0; s < 2; s++) {
                if (s == 0 && !do0) continue;
                const int qg = q0 + s * 64 + w * 16 + fr;
                if (kv0 == q0 + s * 64) {        // diagonal tile for this sub
#pragma unroll
                    for (int kf = 0; kf < 4; kf++)
#pragma unroll
                        for (int r = 0; r < 4; r++)
                            if (kv0 + kf * 16 + g4 * 4 + r > qg)
                                sacc[s][kf][r] = -1e30f;
                }
                float rm = -1e30f;
#pragma unroll
                for (int kf = 0; kf < 4; kf++)
                    rm = fmaxf(rm, fmaxf(fmaxf(sacc[s][kf][0], sacc[s][kf][1]),
                                         fmaxf(sacc[s][kf][2], sacc[s][kf][3])));
                rm = fmaxf(rm, __shfl_xor(rm, 16));
                rm = fmaxf(rm, __shfl_xor(rm, 32));
                if (__any(rm > m_st[s])) {       // exact defer: P <= 1 otherwise
                    float mn   = fmaxf(m_st[s], rm);
                    float corr = fexp2(m_st[s] - mn);
                    l_st[s] *= corr;
#pragma unroll
                    for (int df = 0; df < 8; df++) {
                        accO[s][df][0] *= corr; accO[s][df][1] *= corr;
                        accO[s][df][2] *= corr; accO[s][df][3] *= corr;
                    }
                    m_st[s] = mn;
                }
                float rsum = 0.f;
#pragma unroll
                for (int kf = 0; kf < 4; kf++) {
                    float p0 = fexp2(sacc[s][kf][0] - m_st[s]);
                    float p1 = fexp2(sacc[s][kf][1] - m_st[s]);
                    float p2 = fexp2(sacc[s][kf][2] - m_st[s]);
                    float p3 = fexp2(sacc[s][kf][3] - m_st[s]);
                    rsum += (p0 + p1) + (p2 + p3);
                    s4v pk;
                    pk[0] = (short)f2b(p0); pk[1] = (short)f2b(p1);
                    pk[2] = (short)f2b(p2); pk[3] = (short)f2b(p3);
                    *(s4v*)&Ps[w][(s * 16 + fr) * PP + kf * 16 + g4 * 4] = pk;
                }
                rsum += __shfl_xor(rsum, 16);
                rsum += __shfl_xor(rsum, 32);
                l_st[s] += rsum;
            }

            // O^T += V^T * P^T (shared vf across subs; same-wave Ps RAW ok)
#pragma unroll
            for (int ks = 0; ks < 2; ks++) {
                s8v pf0, pf1;
                if (do0) pf0 = *(const s8v*)&Ps[w][fr * PP + ks * 32 + g4 * 8];
                pf1 = *(const s8v*)&Ps[w][(16 + fr) * PP + ks * 32 + g4 * 8];
#pragma unroll
                for (int df = 0; df < 8; df++) {
                    s8v vf = *(const s8v*)&Vbuf[buf][(df * 16 + fr) * VP +
                                                     ks * 32 + g4 * 8];
                    if (do0) accO[0][df] = mfma16(vf, pf0, accO[0][df]);
                    accO[1][df] = mfma16(vf, pf1, accO[1][df]);
                }
            }

            // write prefetched tile to the other buffer
            if (!last) {
#pragma unroll
                for (int c = 0; c < 4; c++)
                    *(s8v*)&Kbuf[buf ^ 1][(krow + 16 * c) * 128 + (kc8 ^ kxor)] = kreg[c];
#pragma unroll
                for (int c = 0; c < 4; c++)
                    *(s8v*)&Vbuf[buf ^ 1][(32 * c + vd) * VP + vk8] = vreg[c];
            }
            __syncthreads();
        }

        // normalize, transpose O^T -> O through Kbuf ([128][128]), store
        short* OL = (short*)&Kbuf[0][0];
#pragma unroll
        for (int s = 0; s < 2; s++) {
            float inv = 1.f / l_st[s];
#pragma unroll
            for (int df = 0; df < 8; df++) {
                s4v ov;
                ov[0] = (short)f2b(accO[s][df][0] * inv);
                ov[1] = (short)f2b(accO[s][df][1] * inv);
                ov[2] = (short)f2b(accO[s][df][2] * inv);
                ov[3] = (short)f2b(accO[s][df][3] * inv);
                *(s4v*)&OL[(s * 64 + w * 16 + fr) * 128 + ((df * 16 + g4 * 4) ^ xfr)] = ov;
            }
        }
        __syncthreads();
#pragma unroll
        for (int i = 0; i < 8; i++) {
            int row = i * 16 + (t >> 4);
            int ch  = (t & 15) * 8;
            s8v v = *(const s8v*)&OL[row * 128 + (ch ^ ((row & 7) << 3))];
            *(s8v*)(Ob + (size_t)(q0 + row) * D_MODEL + ch) = v;
        }
    }
}

// ---------------------------------------------------------------------------
extern "C" void kernel_launch(void* const* d_in, const int* in_sizes, int n_in,
                              void* d_out, int out_size, void* d_ws, size_t ws_size,
                              hipStream_t stream)
{
    const float* x  = (const float*)d_in[0];
    const float* wq = (const float*)d_in[1];
    const float* wk = (const float*)d_in[2];
    const float* wv = (const float*)d_in[3];
    const float* wo = (const float*)d_in[4];
    const int*   tp = (const int*)d_in[5];

    const int S  = in_sizes[5];
    const int BS = in_sizes[0] / D_MODEL;   // B*S rows (4096)
    const int Bn = BS / S;
    const int NW = D_MODEL * D_MODEL;
    const int NX = BS * D_MODEL;

    // ws (u16 elems): [Q][K][V -> O][Xb -> Vt][Wq][Wk][Wv][Wo] = 96 MB
    u16* Qw  = (u16*)d_ws;
    u16* Kw  = Qw + (size_t)NX;
    u16* Vw  = Kw + (size_t)NX;             // V; reused as attention output O
    u16* Xb  = Vw + (size_t)NX;             // x bf16; reused as V^T
    u16* Wqb = Xb + (size_t)NX;
    u16* Wkb = Wqb + (size_t)NW;
    u16* Wvb = Wkb + (size_t)NW;
    u16* Wob = Wvb + (size_t)NW;

    {
        dim3 g((NX / 8 + 255) / 256, 5);
        cvt_bf16<<<g, 256, 0, stream>>>(x, wq, wk, wv, wo,
                                        Xb, Wqb, Wkb, Wvb, Wob, NX, NW);
    }

    // Q,K,V projections
    dim3 gq(BS / 128, D_MODEL / 128, 3);
    gemm_bt3<u16><<<gq, 256, 0, stream>>>(Xb, Wqb, Wkb, Wvb, Qw, Kw, Vw,
                                          BS, D_MODEL, D_MODEL);

    // RoPE on Q,K (in place); V^T into Xb region (x is dead after QKV GEMM)
    int total = BS * (D_MODEL / 2);
    rope_kernel<<<(total + 255) / 256, 256, 0, stream>>>((u32*)Qw, (u32*)Kw, tp, total, S);
    transpose_v<<<dim3(S / 64, D_MODEL / 64, Bn), 256, 0, stream>>>(Vw, Xb, S);

    // causal flash attention: O (bf16) into the V region (V dead after transpose)
    attn_kernel<<<dim3((S / 256) * NH * Bn, 1, 1), 256, 0, stream>>>(Qw, Kw, Xb, Vw, S);

    // output projection -> fp32 d_out
    dim3 go(BS / 128, D_MODEL / 128, 1);
    gemm_bt3<float><<<go, 256, 0, stream>>>(Vw, Wob, Wob, Wob,
                                            (float*)d_out, (float*)d_out, (float*)d_out,
                                            BS, D_MODEL, D_MODEL);
}